// Round 1
// baseline (308.666 us; speedup 1.0000x reference)
//
#include <hip/hip_runtime.h>
#include <hip/hip_bf16.h>

#define B_    16
#define M_    4096
#define K_    512
#define O_    512

#define BM 128
#define BN 128
#define BK 32

typedef float f32x4 __attribute__((ext_vector_type(4)));
typedef short bf16x8 __attribute__((ext_vector_type(8)));

__device__ __forceinline__ unsigned short f2bf(float f) {
    unsigned int u = __builtin_bit_cast(unsigned int, f);
    u += 0x7fffu + ((u >> 16) & 1u);   // RNE
    return (unsigned short)(u >> 16);
}

// ---------------- kernel 1: s[b,i] = sum_f w[b,f]*A_w[i,f] + A_b[i] ----------------
// grid (B_, 8), block 64. Each block: one b, 64 i values.
__global__ void style_kernel(const float* __restrict__ w, const float* __restrict__ A_w,
                             const float* __restrict__ A_b, float* __restrict__ s) {
    int b = blockIdx.x;
    int i = blockIdx.y * 64 + threadIdx.x;
    __shared__ float wsh[512];
    for (int j = threadIdx.x; j < 512; j += 64) wsh[j] = w[b * 512 + j];
    __syncthreads();
    const float* arow = A_w + (size_t)i * 512;
    float acc = 0.f;
    #pragma unroll 4
    for (int f = 0; f < 512; f += 4) {
        float4 a = *(const float4*)(arow + f);
        acc += a.x * wsh[f] + a.y * wsh[f + 1] + a.z * wsh[f + 2] + a.w * wsh[f + 3];
    }
    s[b * 512 + i] = acc + A_b[i];
}

// ---------------- kernel 2: wd[b,o,i] = bf16( weight[o,i]*s[b,i] * rsqrt(eps+sum_i ...) ) ----
// grid 2048, block 256 (4 waves). One wave per (b,o).
__global__ void demod_kernel(const float* __restrict__ weight, const float* __restrict__ s,
                             unsigned short* __restrict__ wd) {
    int gw = blockIdx.x * 4 + (threadIdx.x >> 6);
    int lane = threadIdx.x & 63;
    int b = gw >> 9;
    int o = gw & 511;
    const float* wrow = weight + (size_t)o * 512;
    const float* srow = s + b * 512;
    float vals[8];
    float ss = 0.f;
    #pragma unroll
    for (int j = 0; j < 8; j++) {
        int i = lane + j * 64;
        float v = wrow[i] * srow[i];
        vals[j] = v;
        ss += v * v;
    }
    #pragma unroll
    for (int off = 32; off; off >>= 1) ss += __shfl_xor(ss, off);
    float nrm = rsqrtf(1e-8f + ss);
    unsigned short* drow = wd + ((size_t)b * 512 + o) * 512;
    #pragma unroll
    for (int j = 0; j < 8; j++) {
        int i = lane + j * 64;
        drow[i] = f2bf(vals[j] * nrm);
    }
}

// ---------------- kernel 3: out[b,n,o] = relu( x[b]·wd[b]^T + bias ) ----------------
// grid (O_/BN, M_/BM, B_), block 256 (2x2 waves of 64x64, each 4x4 of 16x16x32 MFMA)
__global__ __launch_bounds__(256) void gemm_kernel(const float* __restrict__ x,
                                                   const unsigned short* __restrict__ wd,
                                                   const float* __restrict__ bias,
                                                   float* __restrict__ out) {
    __shared__ unsigned short sA[BM * BK];   // x tile, bf16, row-major 128x32
    __shared__ unsigned short sB[BN * BK];   // wd tile, bf16, row-major 128x32 (o-major)

    const int b  = blockIdx.z;
    const int m0 = blockIdx.y * BM;
    const int n0 = blockIdx.x * BN;
    const float* xb = x + (size_t)b * M_ * K_;
    const unsigned short* wdb = wd + (size_t)b * O_ * K_;

    const int t = threadIdx.x;
    const int w = t >> 6;
    const int l = t & 63;
    const int wave_row = (w >> 1) * 64;
    const int wave_col = (w & 1) * 64;
    const int lrow  = l & 15;
    const int khalf = (l >> 4) * 8;

    f32x4 acc[4][4] = {};

    for (int kk = 0; kk < K_; kk += BK) {
        // stage A: fp32 -> bf16 via packed cvt, ds_write 8B
        #pragma unroll
        for (int j = 0; j < 4; j++) {
            int e = (j * 256 + t) * 4;          // element index in 128x32 tile
            int r = e >> 5, c = e & 31;
            float4 v = *(const float4*)(xb + (m0 + r) * K_ + kk + c);
            union { __hip_bfloat162 h2[2]; unsigned long long u64; } cv;
            cv.h2[0] = __float22bfloat162_rn(float2{v.x, v.y});
            cv.h2[1] = __float22bfloat162_rn(float2{v.z, v.w});
            *(unsigned long long*)(&sA[e]) = cv.u64;
        }
        // stage B: bf16 direct global->LDS, 16B per lane, contiguous LDS layout
        #pragma unroll
        for (int j = 0; j < 2; j++) {
            int e = (j * 256 + t) * 8;          // bf16 element index in 128x32 tile
            int r = e >> 5, c = e & 31;
            __builtin_amdgcn_global_load_lds(
                (const __attribute__((address_space(1))) unsigned int*)(wdb + (n0 + r) * K_ + kk + c),
                (__attribute__((address_space(3))) unsigned int*)(&sB[e]),
                16, 0, 0);
        }
        __syncthreads();

        bf16x8 af[4], bfr[4];
        #pragma unroll
        for (int mi = 0; mi < 4; mi++)
            af[mi] = *(const bf16x8*)(&sA[(wave_row + mi * 16 + lrow) * BK + khalf]);
        #pragma unroll
        for (int ni = 0; ni < 4; ni++)
            bfr[ni] = *(const bf16x8*)(&sB[(wave_col + ni * 16 + lrow) * BK + khalf]);
        #pragma unroll
        for (int mi = 0; mi < 4; mi++)
            #pragma unroll
            for (int ni = 0; ni < 4; ni++)
                acc[mi][ni] = __builtin_amdgcn_mfma_f32_16x16x32_bf16(af[mi], bfr[ni], acc[mi][ni], 0, 0, 0);
        __syncthreads();
    }

    // epilogue: C/D layout col=lane&15, row=(lane>>4)*4+reg  [m89-verified]
    const int col_l = l & 15;
    const int row_q = (l >> 4) * 4;
    #pragma unroll
    for (int ni = 0; ni < 4; ni++) {
        int o = n0 + wave_col + ni * 16 + col_l;
        float bv = bias[o];
        #pragma unroll
        for (int mi = 0; mi < 4; mi++) {
            int mrow = m0 + wave_row + mi * 16 + row_q;
            #pragma unroll
            for (int r = 0; r < 4; r++) {
                float v = acc[mi][ni][r] + bv;
                out[((size_t)b * M_ + mrow + r) * O_ + o] = v > 0.f ? v : 0.f;
            }
        }
    }
}

extern "C" void kernel_launch(void* const* d_in, const int* in_sizes, int n_in,
                              void* d_out, int out_size, void* d_ws, size_t ws_size,
                              hipStream_t stream) {
    const float* x      = (const float*)d_in[0];
    const float* w      = (const float*)d_in[1];
    const float* weight = (const float*)d_in[2];
    const float* bias   = (const float*)d_in[3];
    const float* A_w    = (const float*)d_in[4];
    const float* A_b    = (const float*)d_in[5];
    float* out = (float*)d_out;

    unsigned short* wd = (unsigned short*)d_ws;                              // 16*512*512*2 = 8.4 MB
    float* s = (float*)((char*)d_ws + (size_t)B_ * O_ * K_ * sizeof(unsigned short)); // 32 KB

    style_kernel<<<dim3(B_, 8), 64, 0, stream>>>(w, A_w, A_b, s);
    demod_kernel<<<(B_ * O_) / 4, 256, 0, stream>>>(weight, s, wd);
    gemm_kernel<<<dim3(O_ / BN, M_ / BM, B_), 256, 0, stream>>>(x, wd, bias, out);
}

// Round 2
// 306.714 us; speedup vs baseline: 1.0064x; 1.0064x over previous
//
#include <hip/hip_runtime.h>
#include <hip/hip_bf16.h>

#define B_    16
#define M_    4096
#define K_    512
#define O_    512

#define BM 128
#define BN 128
#define BK 32

typedef float f32x4 __attribute__((ext_vector_type(4)));
typedef short bf16x8 __attribute__((ext_vector_type(8)));
typedef unsigned short u16x8 __attribute__((ext_vector_type(8)));

// LDS chunk swizzle: tile is 128 rows x 4 k-quads of 16B chunks.
// chunk(row,kq) = row*4 + (kq ^ ((row>>1)&3))  -> <=2-way bank access on both
// the staging-write and fragment-read patterns (2-way is free on gfx950).
__device__ __forceinline__ int chunk_off(int row, int kq) {
    return (row * 4 + (kq ^ ((row >> 1) & 3))) * 8;   // ushort offset
}

// ---------------- kernel 1: s[b,i] = sum_f w[b,f]*A_w[i,f] + A_b[i] ----------------
__global__ void style_kernel(const float* __restrict__ w, const float* __restrict__ A_w,
                             const float* __restrict__ A_b, float* __restrict__ s) {
    int b = blockIdx.x;
    int i = blockIdx.y * 64 + threadIdx.x;
    __shared__ float wsh[512];
    for (int j = threadIdx.x; j < 512; j += 64) wsh[j] = w[b * 512 + j];
    __syncthreads();
    const float* arow = A_w + (size_t)i * 512;
    float acc = 0.f;
    #pragma unroll 4
    for (int f = 0; f < 512; f += 4) {
        float4 a = *(const float4*)(arow + f);
        acc += a.x * wsh[f] + a.y * wsh[f + 1] + a.z * wsh[f + 2] + a.w * wsh[f + 3];
    }
    s[b * 512 + i] = acc + A_b[i];
}

// ---------------- kernel 2: wd[b,o,i] = bf16(demodulated weight) ----------------
__global__ void demod_kernel(const float* __restrict__ weight, const float* __restrict__ s,
                             unsigned short* __restrict__ wd) {
    int gw = blockIdx.x * 4 + (threadIdx.x >> 6);
    int lane = threadIdx.x & 63;
    int b = gw >> 9;
    int o = gw & 511;
    const float* wrow = weight + (size_t)o * 512;
    const float* srow = s + b * 512;
    float vals[8];
    float ss = 0.f;
    #pragma unroll
    for (int j = 0; j < 8; j++) {
        int i = lane + j * 64;
        float v = wrow[i] * srow[i];
        vals[j] = v;
        ss += v * v;
    }
    #pragma unroll
    for (int off = 32; off; off >>= 1) ss += __shfl_xor(ss, off);
    float nrm = rsqrtf(1e-8f + ss);
    unsigned short* drow = wd + ((size_t)b * 512 + o) * 512;
    #pragma unroll
    for (int j = 0; j < 8; j++) {
        int i = lane + j * 64;
        unsigned int u = __builtin_bit_cast(unsigned int, vals[j] * nrm);
        u += 0x7fffu + ((u >> 16) & 1u);
        drow[i] = (unsigned short)(u >> 16);
    }
}

// ---------------- kernel 3: out[b,n,o] = relu( x[b]·wd[b]^T + bias ) ----------------
__global__ __launch_bounds__(256, 3) void gemm_kernel(const float* __restrict__ x,
                                                      const unsigned short* __restrict__ wd,
                                                      const float* __restrict__ bias,
                                                      float* __restrict__ out) {
    // double-buffered, chunk-swizzled tiles (8 KB each)
    __shared__ unsigned short sA[2][BM * BK];
    __shared__ unsigned short sB[2][BN * BK];

    // XCD swizzle: consecutive blocks round-robin XCDs; give each XCD a
    // contiguous mb range (2 b-values -> wd slice 1MB L2-resident) and put the
    // 4 n-blocks sharing an x-tile back-to-back on the same XCD.
    int g = blockIdx.x;
    int xcd = g & 7;
    int grp = g >> 3;                  // [0,256)
    int nblk = grp & 3;
    int mb = xcd * 64 + (grp >> 2);    // [0,512)
    const int b  = mb >> 5;
    const int m0 = (mb & 31) * BM;
    const int n0 = nblk * BN;

    const float* xb = x + (size_t)b * M_ * K_;
    const unsigned short* wdb = wd + (size_t)b * O_ * K_;

    const int t = threadIdx.x;
    const int w = t >> 6;
    const int l = t & 63;
    const int wave_row = (w >> 1) * 64;
    const int wave_col = (w & 1) * 64;
    const int lrow  = l & 15;
    const int kq_l  = l >> 4;

    // iteration-invariant fragment offsets (swizzled)
    int offA[4], offB[4];
    #pragma unroll
    for (int mi = 0; mi < 4; mi++)
        offA[mi] = chunk_off(wave_row + mi * 16 + lrow, kq_l);
    #pragma unroll
    for (int ni = 0; ni < 4; ni++)
        offB[ni] = chunk_off(wave_col + ni * 16 + lrow, kq_l);

    // A staging geometry: thread t covers row r = t>>1, 16 floats starting at (t&1)*16
    const int ar = t >> 1;
    const int akq0 = (t & 1) * 2;
    const float* abase = xb + (size_t)(m0 + ar) * K_ + akq0 * 8;

    // B staging geometry: instr j writes chunks [w*128 + j*64 + lane]
    int bchunk[2], brow[2], bkq[2];
    #pragma unroll
    for (int j = 0; j < 2; j++) {
        int c = w * 128 + j * 64 + l;
        brow[j] = c >> 2;
        bkq[j] = (c & 3) ^ ((brow[j] >> 1) & 3);
        bchunk[j] = c;
    }

    f32x4 acc[4][4] = {};
    f32x4 areg[4];

    // ---- prologue: stage tile 0 into buffer 0 ----
    #pragma unroll
    for (int j = 0; j < 2; j++) {
        __builtin_amdgcn_global_load_lds(
            (const __attribute__((address_space(1))) unsigned int*)(wdb + (size_t)(n0 + brow[j]) * K_ + bkq[j] * 8),
            (__attribute__((address_space(3))) unsigned int*)(&sB[0][bchunk[j] * 8]),
            16, 0, 0);
    }
    #pragma unroll
    for (int j = 0; j < 4; j++) areg[j] = *(const f32x4*)(abase + j * 4);
    #pragma unroll
    for (int j = 0; j < 2; j++) {
        union { __hip_bfloat162 h[4]; u16x8 v; } cv;
        cv.h[0] = __float22bfloat162_rn(float2{areg[2*j][0], areg[2*j][1]});
        cv.h[1] = __float22bfloat162_rn(float2{areg[2*j][2], areg[2*j][3]});
        cv.h[2] = __float22bfloat162_rn(float2{areg[2*j+1][0], areg[2*j+1][1]});
        cv.h[3] = __float22bfloat162_rn(float2{areg[2*j+1][2], areg[2*j+1][3]});
        *(u16x8*)(&sA[0][chunk_off(ar, akq0 + j)]) = cv.v;
    }
    __syncthreads();

    // ---- main loop: single barrier per iteration ----
    int cur = 0;
    #pragma unroll 2
    for (int kk = 0; kk < K_; kk += BK) {
        int nxt = cur ^ 1;
        bool pf = (kk + BK) < K_;
        if (pf) {
            // prefetch tile k+1: B via DMA into sB[nxt], A into registers
            #pragma unroll
            for (int j = 0; j < 2; j++) {
                __builtin_amdgcn_global_load_lds(
                    (const __attribute__((address_space(1))) unsigned int*)(wdb + (size_t)(n0 + brow[j]) * K_ + kk + BK + bkq[j] * 8),
                    (__attribute__((address_space(3))) unsigned int*)(&sB[nxt][bchunk[j] * 8]),
                    16, 0, 0);
            }
            #pragma unroll
            for (int j = 0; j < 4; j++) areg[j] = *(const f32x4*)(abase + kk + BK + j * 4);
        }

        // compute on tile k
        bf16x8 af[4], bfr[4];
        #pragma unroll
        for (int mi = 0; mi < 4; mi++) af[mi] = *(const bf16x8*)(&sA[cur][offA[mi]]);
        #pragma unroll
        for (int ni = 0; ni < 4; ni++) bfr[ni] = *(const bf16x8*)(&sB[cur][offB[ni]]);
        #pragma unroll
        for (int mi = 0; mi < 4; mi++)
            #pragma unroll
            for (int ni = 0; ni < 4; ni++)
                acc[mi][ni] = __builtin_amdgcn_mfma_f32_16x16x32_bf16(af[mi], bfr[ni], acc[mi][ni], 0, 0, 0);

        if (pf) {
            // convert + store A tile k+1 into sA[nxt]
            #pragma unroll
            for (int j = 0; j < 2; j++) {
                union { __hip_bfloat162 h[4]; u16x8 v; } cv;
                cv.h[0] = __float22bfloat162_rn(float2{areg[2*j][0], areg[2*j][1]});
                cv.h[1] = __float22bfloat162_rn(float2{areg[2*j][2], areg[2*j][3]});
                cv.h[2] = __float22bfloat162_rn(float2{areg[2*j+1][0], areg[2*j+1][1]});
                cv.h[3] = __float22bfloat162_rn(float2{areg[2*j+1][2], areg[2*j+1][3]});
                *(u16x8*)(&sA[nxt][chunk_off(ar, akq0 + j)]) = cv.v;
            }
        }
        __syncthreads();   // drains lgkm (ds_writes) + vmcnt (B DMA k+1), covered by MFMA phase
        cur = nxt;
    }

    // epilogue: C/D layout col=lane&15, row=(lane>>4)*4+reg  [m89-verified]
    const int col_l = l & 15;
    const int row_q = (l >> 4) * 4;
    #pragma unroll
    for (int ni = 0; ni < 4; ni++) {
        int o = n0 + wave_col + ni * 16 + col_l;
        float bv = bias[o];
        #pragma unroll
        for (int mi = 0; mi < 4; mi++) {
            int mrow = m0 + wave_row + mi * 16 + row_q;
            #pragma unroll
            for (int r = 0; r < 4; r++) {
                float v = acc[mi][ni][r] + bv;
                out[((size_t)b * M_ + mrow + r) * O_ + o] = v > 0.f ? v : 0.f;
            }
        }
    }
}

extern "C" void kernel_launch(void* const* d_in, const int* in_sizes, int n_in,
                              void* d_out, int out_size, void* d_ws, size_t ws_size,
                              hipStream_t stream) {
    const float* x      = (const float*)d_in[0];
    const float* w      = (const float*)d_in[1];
    const float* weight = (const float*)d_in[2];
    const float* bias   = (const float*)d_in[3];
    const float* A_w    = (const float*)d_in[4];
    const float* A_b    = (const float*)d_in[5];
    float* out = (float*)d_out;

    unsigned short* wd = (unsigned short*)d_ws;                              // 8.4 MB
    float* s = (float*)((char*)d_ws + (size_t)B_ * O_ * K_ * sizeof(unsigned short));

    style_kernel<<<dim3(B_, 8), 64, 0, stream>>>(w, A_w, A_b, s);
    demod_kernel<<<(B_ * O_) / 4, 256, 0, stream>>>(weight, s, wd);
    gemm_kernel<<<2048, 256, 0, stream>>>(x, wd, bias, out);
}